// Round 8
// baseline (241.938 us; speedup 1.0000x reference)
//
#include <hip/hip_runtime.h>

// MiniGPT fused forward. Inputs fp32 (x int32/int64 auto), OUTPUT fp32 (proven r5).
// R8: pipeline round. attn: K LDS double-buffer + issue-early/write-late staging (T14),
// ONE barrier/tile, V direct-from-global regs (v_lds deleted). qkv: 768 blocks
// (matrix-split), 3 blocks/CU. tok_prep parallelized. Softmax/relayout = r7 (verified).
// ws: Q | K | Vt (bf16, 8MB each) | Wb (384KB) | tokidx  (~24.6MB, guarded).

#define TWIN 2048
#define NEMB 256
#define NB   8
#define VOCAB 50257
#define NTOK (NB * TWIN)

typedef __attribute__((ext_vector_type(8))) short s16x8;
typedef __attribute__((ext_vector_type(4))) float f32x4;
typedef __attribute__((ext_vector_type(4))) float f4;
typedef unsigned short u16;
typedef unsigned int   u32;

__device__ __forceinline__ u16 f2bf(float f) {
    union { float f; u32 i; } x; x.f = f;
    u32 r = x.i + 0x7fffu + ((x.i >> 16) & 1u);
    return (u16)(r >> 16);
}
__device__ __forceinline__ u32 pack2bf(float a, float b) {
    return (u32)f2bf(a) | ((u32)f2bf(b) << 16);
}

// ---------------- W fp32 -> bf16, once ----------------
__global__ __launch_bounds__(256) void wconv_kernel(
    const float* __restrict__ Wq, const float* __restrict__ Wk,
    const float* __restrict__ Wv, u16* __restrict__ Wb)
{
    int b = blockIdx.x;
    int which = b >> 5;
    int off = (b & 31) * 2048 + threadIdx.x * 8;
    const float* src = (which == 0) ? Wq : ((which == 1) ? Wk : Wv);
    f4 v0 = *(const f4*)(src + off);
    f4 v1 = *(const f4*)(src + off + 4);
    u16 ww[8];
#pragma unroll
    for (int i = 0; i < 4; i++) { ww[i] = f2bf(v0[i]); ww[4 + i] = f2bf(v1[i]); }
    *(uint4*)(Wb + which * 65536 + off) = *(uint4*)ww;
}

// ---------------- token index prep (parallel; int32/int64 vote on first 128B) -------
__global__ __launch_bounds__(256) void tok_prep(const void* xraw, int* tokidx) {
    const long long* x64 = (const long long*)xraw;
    const int*       x32 = (const int*)xraw;
    long long probe = x64[threadIdx.x & 63];          // same 64 pairs for every wave
    int ok = (probe >= 0 && probe < VOCAB) ? 1 : 0;   // int32 data read as int64 -> >=2^32
    int is64 = __all(ok);
    int i = blockIdx.x * 256 + threadIdx.x;
    int v = is64 ? (int)x64[i] : x32[i];
    tokidx[i] = (v < 0) ? 0 : ((v >= VOCAB) ? (VOCAB - 1) : v);
}

// ---------------- Kernel A: h build + one-matrix projection per block ----------------
// grid 768 = 3 matrices x 256 t-blocks (64 rows). 256 thr (4 waves). LDS 32KB -> 3 blk/CU.
__global__ __launch_bounds__(256) void qkv_kernel(
    const int* __restrict__ tokidx,
    const float* __restrict__ tok, const float* __restrict__ pos,
    const u16* __restrict__ Wb,
    const float* __restrict__ bqp, const float* __restrict__ bkp,
    const float* __restrict__ bvp,
    u16* __restrict__ Qg, u16* __restrict__ Kg, u16* __restrict__ Vt)
{
    __shared__ u16 h_lds[64 * 256];      // h (swizzled), then reused as out staging

    const int tid   = threadIdx.x;
    const int which = blockIdx.x >> 8;               // 0=Q 1=K 2=V
    const int t0    = (blockIdx.x & 255) * 64;
    const int bb    = t0 >> 11;
    const int tl0   = t0 & (TWIN - 1);

    // build h = bf16(tok[x[t]] + pos[t]) into swizzled LDS
#pragma unroll
    for (int j = 0; j < 8; j++) {
        int c   = tid + 256 * j;
        int row = c >> 5, col = c & 31;
        int t   = t0 + row;
        int xi  = tokidx[t];
        const float* tp = tok + (size_t)xi * NEMB + col * 8;
        const float* pp = pos + (size_t)(t & (TWIN - 1)) * NEMB + col * 8;
        f4 a0 = *(const f4*)tp, a1 = *(const f4*)(tp + 4);
        f4 b0 = *(const f4*)pp, b1 = *(const f4*)(pp + 4);
        u16 hh[8];
#pragma unroll
        for (int i = 0; i < 4; i++) {
            hh[i]     = f2bf(a0[i] + b0[i]);
            hh[4 + i] = f2bf(a1[i] + b1[i]);
        }
        *(uint4*)((char*)h_lds + row * 512 + ((col * 16) ^ ((row & 7) << 4))) = *(uint4*)hh;
    }
    __syncthreads();

    const int wid = tid >> 6, lane = tid & 63, g = lane >> 4, lr = lane & 15;
    const u16* Wp = Wb + which * 65536;
    const float* Bp = (which == 0) ? bqp : ((which == 1) ? bkp : bvp);

    f32x4 acc[16];
#pragma unroll
    for (int i = 0; i < 16; i++) acc[i] = (f32x4){0.f, 0.f, 0.f, 0.f};

#pragma unroll
    for (int es = 0; es < 8; es++) {
        int arow = wid * 16 + lr;
        s16x8 af = *(const s16x8*)((const char*)h_lds + arow * 512 +
                                   ((es * 64 + g * 16) ^ ((arow & 7) << 4)));
        s16x8 bfv[16];
#pragma unroll
        for (int ct = 0; ct < 16; ct++)
            bfv[ct] = *(const s16x8*)(Wp + (size_t)(ct * 16 + lr) * NEMB + es * 32 + g * 8);
#pragma unroll
        for (int ct = 0; ct < 16; ct++)
            acc[ct] = __builtin_amdgcn_mfma_f32_16x16x32_bf16(af, bfv[ct], acc[ct], 0, 0, 0);
    }

    if (which < 2) {
        u16* dst = (which == 0) ? Qg : Kg;
        __syncthreads();                              // all h reads done; reuse h_lds
#pragma unroll
        for (int ct = 0; ct < 16; ct++) {
            float bias = Bp[ct * 16 + lr];
#pragma unroll
            for (int r = 0; r < 4; r++)
                h_lds[(wid * 16 + 4 * g + r) * 256 + ct * 16 + lr] = f2bf(acc[ct][r] + bias);
        }
        __syncthreads();
#pragma unroll
        for (int j = 0; j < 8; j++) {
            int c = tid + 256 * j;
            int row = c >> 5, col = c & 31;
            uint4 v = *(const uint4*)(h_lds + row * 256 + col * 8);
            *(uint4*)(dst + (size_t)(t0 + row) * NEMB + col * 8) = v;
        }
    } else {
        // V: transposed store Vt[b][e][t]
#pragma unroll
        for (int ct = 0; ct < 16; ct++) {
            float bias = Bp[ct * 16 + lr];
            u16 pk[4];
#pragma unroll
            for (int r = 0; r < 4; r++) pk[r] = f2bf(acc[ct][r] + bias);
            int e = ct * 16 + lr;
            *(ushort4*)(Vt + ((size_t)bb * NEMB + e) * TWIN + tl0 + wid * 16 + 4 * g)
                = *(ushort4*)pk;
        }
    }
}

// ---------------- Kernel B: causal flash attention, pipelined ----------------
// 512 blocks x 128 thr (2 waves, qsub split). KTILE=32. K: LDS dbuf + T14 reg staging,
// ONE barrier/tile. V: direct-from-global regs. Softmax/relayout identical to r7.
__global__ __launch_bounds__(128) void attn_kernel(
    const u16* __restrict__ Qg, const u16* __restrict__ Kg,
    const u16* __restrict__ Vt, float* __restrict__ outp)
{
    __shared__ u16 k_lds[2][32 * 256];   // 2 x 16KB, linear dest, swizzle via source

    const int tid = threadIdx.x;
    const int bid = blockIdx.x;
    const int bb  = bid & 7;
    const int idx = bid >> 3;
    const int qtile = (idx < 32) ? (63 - idx) : (idx - 32);   // pair-balanced
    const int q0 = qtile * 32;
    const int nt = qtile + 1;

    const u16* Qb = Qg + (size_t)bb * TWIN * NEMB;
    const u16* Kb = Kg + (size_t)bb * TWIN * NEMB;
    const u16* Vb = Vt + (size_t)bb * NEMB * TWIN;
    float* Ob = outp + (size_t)bb * TWIN * NEMB;

    const int wid = tid >> 6, lane = tid & 63;
    const int q   = lane & 15, hi = lane >> 4;
    const int qrow = q0 + wid * 16 + q;

    s16x8 qf[8];
#pragma unroll
    for (int es = 0; es < 8; es++)
        qf[es] = *(const s16x8*)(Qb + (size_t)qrow * NEMB + es * 32 + hi * 8);

    f32x4 o[16];
#pragma unroll
    for (int i = 0; i < 16; i++) o[i] = (f32x4){0.f, 0.f, 0.f, 0.f};
    float m = -1.0e4f, l = 0.f;

    // prologue: stage K tile 0 into buf 0
    {
#pragma unroll
        for (int j = 0; j < 8; j++) {
            int c = tid + 128 * j;
            int row = c >> 5;
            int colb = ((c & 31) * 16) ^ ((row & 7) << 4);
            uint4 v = *(const uint4*)((const char*)(Kb + (size_t)row * NEMB) + colb);
            *(uint4*)((char*)k_lds[0] + c * 16) = v;
        }
        __syncthreads();
    }

    for (int t = 0; t < nt; t++) {
        const int kb = t * 32;
        const char* kbase = (const char*)k_lds[t & 1];

        // (1) issue next K tile loads EARLY (latency hides under compute of tile t)
        uint4 kreg[8];
        if (t + 1 < nt) {
            const int kbn = kb + 32;
#pragma unroll
            for (int j = 0; j < 8; j++) {
                int c = tid + 128 * j;
                int row = c >> 5;
                int colb = ((c & 31) * 16) ^ ((row & 7) << 4);
                kreg[j] = *(const uint4*)((const char*)(Kb + (size_t)(kbn + row) * NEMB) + colb);
            }
        }
        // (2) issue V fragment loads for tile t (consumed at PV, ~600cy later)
        s16x8 vf[16];
#pragma unroll
        for (int et = 0; et < 16; et++)
            vf[et] = *(const s16x8*)(Vb + (size_t)(q + 16 * et) * TWIN + kb + hi * 8);

        // (3) S^T = K·Q^T from LDS buffer
        f32x4 st0 = (f32x4){0.f, 0.f, 0.f, 0.f};
        f32x4 st1 = (f32x4){0.f, 0.f, 0.f, 0.f};
#pragma unroll
        for (int es = 0; es < 8; es++) {
            s16x8 kf0 = *(const s16x8*)(kbase + q * 512 +
                                        ((es * 64 + hi * 16) ^ ((q & 7) << 4)));
            st0 = __builtin_amdgcn_mfma_f32_16x16x32_bf16(kf0, qf[es], st0, 0, 0, 0);
            int row1 = q + 16;
            s16x8 kf1 = *(const s16x8*)(kbase + row1 * 512 +
                                        ((es * 64 + hi * 16) ^ ((row1 & 7) << 4)));
            st1 = __builtin_amdgcn_mfma_f32_16x16x32_bf16(kf1, qf[es], st1, 0, 0, 0);
        }

        // causal mask (diagonal tile only)
        if (t == nt - 1) {
#pragma unroll
            for (int r = 0; r < 4; r++) {
                if (kb + 4 * hi + r > qrow)      st0[r] = -1.0e4f;
                if (kb + 16 + 4 * hi + r > qrow) st1[r] = -1.0e4f;
            }
        }

        // in-register softmax (lane owns its q; 2 shfl cross-hi)
        float tm = fmaxf(fmaxf(fmaxf(st0[0], st0[1]), fmaxf(st0[2], st0[3])),
                         fmaxf(fmaxf(st1[0], st1[1]), fmaxf(st1[2], st1[3])));
        tm = fmaxf(tm, __shfl_xor(tm, 16));
        tm = fmaxf(tm, __shfl_xor(tm, 32));
        if (__any(tm > m)) {
            float mn = fmaxf(m, tm);
            float sc = __expf(m - mn);
            m = mn; l *= sc;
            float scr[4];
#pragma unroll
            for (int r = 0; r < 4; r++) scr[r] = __shfl(sc, hi * 20 + r);
#pragma unroll
            for (int et = 0; et < 16; et++)
#pragma unroll
                for (int r = 0; r < 4; r++) o[et][r] *= scr[r];
        }
        float p0[4], p1[4];
#pragma unroll
        for (int r = 0; r < 4; r++) {
            p0[r] = __expf(st0[r] - m);
            p1[r] = __expf(st1[r] - m);
        }
        float rs = (p0[0] + p0[1]) + (p0[2] + p0[3]) + (p1[0] + p1[1]) + (p1[2] + p1[3]);
        rs += __shfl_xor(rs, 16);
        rs += __shfl_xor(rs, 32);
        l += rs;

        // P -> A-frag relayout in-register (8 shfl + select) -- r7 verified
        u32 pk00 = pack2bf(p0[0], p0[1]), pk01 = pack2bf(p0[2], p0[3]);
        u32 pk10 = pack2bf(p1[0], p1[1]), pk11 = pack2bf(p1[2], p1[3]);
        int sA = (lane & 15) | ((lane & 16) << 1);
        int sB = sA + 16;
        u32 b00 = (u32)__shfl((int)pk00, sA), b01 = (u32)__shfl((int)pk01, sA);
        u32 b02 = (u32)__shfl((int)pk00, sB), b03 = (u32)__shfl((int)pk01, sB);
        u32 b10 = (u32)__shfl((int)pk10, sA), b11 = (u32)__shfl((int)pk11, sA);
        u32 b12 = (u32)__shfl((int)pk10, sB), b13 = (u32)__shfl((int)pk11, sB);
        bool c1 = (hi & 2) != 0;
        union { uint4 u; s16x8 v; } pu;
        pu.u.x = c1 ? b10 : b00;
        pu.u.y = c1 ? b11 : b01;
        pu.u.z = c1 ? b12 : b02;
        pu.u.w = c1 ? b13 : b03;
        s16x8 pf = pu.v;

        // (4) O += P V from registers (no LDS)
#pragma unroll
        for (int et = 0; et < 16; et++)
            o[et] = __builtin_amdgcn_mfma_f32_16x16x32_bf16(pf, vf[et], o[et], 0, 0, 0);

        // (5) write next K tile late; single barrier
        if (t + 1 < nt) {
#pragma unroll
            for (int j = 0; j < 8; j++)
                *(uint4*)((char*)k_lds[(t + 1) & 1] + (tid + 128 * j) * 16) = kreg[j];
        }
        __syncthreads();
    }

    // epilogue: per-row 1/l via shfl, direct fp32 stores
    float rinv = 1.0f / l;
    float invr[4];
#pragma unroll
    for (int r = 0; r < 4; r++) invr[r] = __shfl(rinv, hi * 20 + r);
#pragma unroll
    for (int et = 0; et < 16; et++) {
#pragma unroll
        for (int r = 0; r < 4; r++)
            Ob[(size_t)(q0 + wid * 16 + 4 * hi + r) * NEMB + q + 16 * et]
                = o[et][r] * invr[r];
    }
}

// ---------------- ws-too-small diagnostic ----------------
__global__ __launch_bounds__(256) void ws_diag(float* outp, int n, float val) {
    int i = blockIdx.x * 256 + threadIdx.x;
    if (i < n) outp[i] = (i == 0) ? val : 0.0f;
}

extern "C" void kernel_launch(void* const* d_in, const int* in_sizes, int n_in,
                              void* d_out, int out_size, void* d_ws, size_t ws_size,
                              hipStream_t stream)
{
    const void*  x   = d_in[0];
    const float* tok = (const float*)d_in[1];
    const float* pos = (const float*)d_in[2];
    const float* Wq  = (const float*)d_in[3];
    const float* bq  = (const float*)d_in[4];
    const float* Wk  = (const float*)d_in[5];
    const float* bk  = (const float*)d_in[6];
    const float* Wv  = (const float*)d_in[7];
    const float* bv  = (const float*)d_in[8];

    const size_t kvElems = (size_t)NB * TWIN * NEMB;
    const size_t need = 3 * kvElems * 2 + 3 * 65536 * 2 + NTOK * 4 + 64;

    if (ws_size < need) {
        float val = 1000.0f + (float)(ws_size >> 20);
        hipLaunchKernelGGL(ws_diag, dim3((out_size + 255) / 256), dim3(256), 0, stream,
                           (float*)d_out, out_size, val);
        return;
    }

    u16* Qg = (u16*)d_ws;
    u16* Kg = Qg + kvElems;
    u16* Vt = Kg + kvElems;
    u16* Wb = Vt + kvElems;
    int* tokidx = (int*)(Wb + 3 * 65536);

    hipLaunchKernelGGL(wconv_kernel, dim3(96), dim3(256), 0, stream, Wq, Wk, Wv, Wb);
    hipLaunchKernelGGL(tok_prep, dim3(64), dim3(256), 0, stream, x, tokidx);
    hipLaunchKernelGGL(qkv_kernel, dim3(768), dim3(256), 0, stream,
                       tokidx, tok, pos, Wb, bq, bk, bv, Qg, Kg, Vt);
    hipLaunchKernelGGL(attn_kernel, dim3(512), dim3(128), 0, stream,
                       Qg, Kg, Vt, (float*)d_out);
}